// Round 8
// baseline (269.440 us; speedup 1.0000x reference)
//
#include <hip/hip_runtime.h>
#include <hip/hip_bf16.h>
#include <math.h>

// MMD loss, N=8192 D=128 fp32 in, scalar fp32 out.
// Numerics (validated R1-R7, absmax 0): reference's (sum(Kxx)-trace) cancels to
// exactly 0 in fp32; answer = -2*S_xy/N^2 via emulated fp32 absorption. bf16
// MFMA approximates d2; d2<140 -> exact fp32 re-dot (rare); 140..155 -> approx
// exp (truncation past 155: ~2e-7 relative); else skip. Terms scaled e^{+128}.
//
// R8: R3's proven 2-blocks/CU single-shot-K structure (the only latency hiding
// that works here is cross-block overlap, m114; barriers drain vmcnt so intra-
// block ping-pong is unreachable -- R7 lesson). Changes vs R3: 64x64 wave
// tiles at 256 thr (0.5 ds_read/MFMA vs 0.75 -> LDS pipe 31->21us), approx
// tier 170->155 (exp-body rate 20%->5%), finalize fused via done-counter
// (R5-validated). launch_bounds(256,2) + b[4]/one-a liveness -> no spill.

#define NPTS 8192
#define DDIM 128
#define NBLK 8256   // 2080 xx + 2080 yy + 4096 xy (128x128 tiles)

typedef __bf16 bf16x8 __attribute__((ext_vector_type(8)));
typedef float f32x4 __attribute__((ext_vector_type(4)));

// async 16B global->LDS (per-lane global addr; LDS dest = uniform base + lane*16)
#define ASYNC_LD16(gp, lp)                                                        \
    __builtin_amdgcn_global_load_lds(                                             \
        (const __attribute__((address_space(1))) unsigned int*)(gp),              \
        (__attribute__((address_space(3))) unsigned int*)(lp), 16, 0, 0)

// ws layout:
//   0       : double part[8256]  (66048 B per-block partials, scaled e^{+128})
//   66304   : uint done
//   66560   : float x2[8192]
//   99328   : float y2[8192]
//   132096  : __bf16 Zb [8192*128]  (2 MB)
//   2229248 : __bf16 Zpb[8192*128]  (2 MB)
__global__ void prep_kernel(const float* __restrict__ Z, const float* __restrict__ Zp,
                            float* __restrict__ x2, float* __restrict__ y2,
                            __bf16* __restrict__ Zb, __bf16* __restrict__ Zpb,
                            unsigned* __restrict__ done) {
    if (blockIdx.x == 0 && threadIdx.x == 0) *done = 0u;
    const int row = blockIdx.x * 16 + (threadIdx.x >> 4);   // 0..16383
    const int sub = threadIdx.x & 15;
    const float* src; float* nrm; __bf16* dst; int r;
    if (row < NPTS) { src = Z;  nrm = x2; dst = Zb;  r = row; }
    else            { src = Zp; nrm = y2; dst = Zpb; r = row - NPTS; }
    const float4* p = (const float4*)(src + (size_t)r * DDIM) + sub * 2;
    float4 a = p[0], b = p[1];
    float s = a.x*a.x + a.y*a.y + a.z*a.z + a.w*a.w
            + b.x*b.x + b.y*b.y + b.z*b.z + b.w*b.w;
    bf16x8 o = { (__bf16)a.x, (__bf16)a.y, (__bf16)a.z, (__bf16)a.w,
                 (__bf16)b.x, (__bf16)b.y, (__bf16)b.z, (__bf16)b.w };
    *(bf16x8*)(dst + (size_t)r * DDIM + sub * 8) = o;
    #pragma unroll
    for (int off = 8; off; off >>= 1) s += __shfl_down(s, off, 16);
    if (sub == 0) nrm[r] = s;
}

__launch_bounds__(256, 2)
__global__ void mmd_gemm(const float* __restrict__ Z, const float* __restrict__ Zp,
                         const __bf16* __restrict__ Zb, const __bf16* __restrict__ Zpb,
                         const float* __restrict__ x2g, const float* __restrict__ y2g,
                         double* __restrict__ part, unsigned* __restrict__ done,
                         float* __restrict__ out) {
    // ---- decode linear block id -> (mat, br, bc); triangles packed
    const int bid = blockIdx.x;
    int mat, br, bc;
    if (bid < 4160) {
        mat = (bid < 2080) ? 0 : 1;
        int idx = bid - mat * 2080;
        int r = (int)((sqrtf(8.f * (float)idx + 1.f) - 1.f) * 0.5f);
        while ((r + 1) * (r + 2) / 2 <= idx) ++r;
        while (r * (r + 1) / 2 > idx) --r;
        br = idx - r * (r + 1) / 2;   // br <= bc: upper triangle
        bc = r;
    } else {
        mat = 2;
        int idx = bid - 4160;
        br = idx >> 6; bc = idx & 63;
    }
    const float*  Xf = (mat == 1) ? Zp  : Z;
    const float*  Yf = (mat == 0) ? Z   : Zp;
    const __bf16* Xb = (mat == 1) ? Zpb : Zb;
    const __bf16* Yb = (mat == 0) ? Zb  : Zpb;
    const float*  xn = (mat == 1) ? y2g : x2g;
    const float*  yn = (mat == 0) ? x2g : y2g;

    __shared__ __bf16 As[128 * DDIM];   // 32 KB, XOR-swizzled 16B chunks
    __shared__ __bf16 Bs[128 * DDIM];   // 32 KB
    __shared__ float x2s[128], y2s[128];
    __shared__ float red[4];
    __shared__ double redd[3][4];
    __shared__ int lastFlag;

    const int tid = threadIdx.x;
    const int w = tid >> 6, lane = tid & 63;

    // ---- stage bf16 tiles via global_load_lds; LDS[row][s] = G[row][s^(row&15)]
    // waves 0-1 -> A (16 x 1KB insts each), waves 2-3 -> B. Bank-verified geometry.
    {
        const __bf16* src = (w < 2) ? (Xb + (size_t)br * 128 * DDIM)
                                    : (Yb + (size_t)bc * 128 * DDIM);
        char* dstB = (char*)((w < 2) ? As : Bs);
        const int wh = w & 1;
        #pragma unroll
        for (int t = 0; t < 16; t++) {
            int row = wh * 64 + t * 4 + (lane >> 4);
            int c = (lane & 15) ^ (row & 15);
            ASYNC_LD16(src + (size_t)row * DDIM + c * 8, dstB + wh * 16384 + t * 1024);
        }
    }
    if (tid < 128) x2s[tid]       = xn[br * 128 + tid];
    else           y2s[tid - 128] = yn[bc * 128 + (tid - 128)];
    __syncthreads();

    // ---- MFMA: 4 waves in 2x2, each 64x64 (4x4 frags of 16x16x32).
    // Liveness: b[4] + one a (acc 64 + b 16 + a 4 regs; budget 256 at 2 w/SIMD).
    const int lr = lane & 15;
    const int q  = lane >> 4;           // 0..3
    const int wm0 = (w >> 1) * 64;
    const int wn0 = (w & 1) * 64;

    f32x4 acc[4][4] = {};
    #pragma unroll
    for (int ks = 0; ks < 4; ks++) {
        const int chunk = ks * 4 + q;
        bf16x8 bfr[4];
        #pragma unroll
        for (int f = 0; f < 4; f++) {
            int rb = wn0 + f * 16 + lr;
            bfr[f] = *(const bf16x8*)((const char*)Bs + rb * 256 + ((chunk ^ lr) * 16));
        }
        #pragma unroll
        for (int fm = 0; fm < 4; fm++) {
            int ra = wm0 + fm * 16 + lr;
            bf16x8 afr = *(const bf16x8*)((const char*)As + ra * 256 + ((chunk ^ lr) * 16));
            #pragma unroll
            for (int fn = 0; fn < 4; fn++)
                acc[fm][fn] = __builtin_amdgcn_mfma_f32_16x16x32_bf16(
                    afr, bfr[fn], acc[fm][fn], 0, 0, 0);
        }
    }

    // ---- epilogue: fast path = 1 fma + 1 cmp; approx tier (d2<155) = fma+exp;
    // exact tier (d2<140) = fp32 re-dot. C/D: col=lane&15, row=q*4+reg [m89/m91]
    const bool isDiag = (mat < 2) && (br == bc);
    float t155[4], syv[4], e128h[4];
    #pragma unroll
    for (int fn = 0; fn < 4; fn++) {
        float s = y2s[wn0 + fn * 16 + lr];
        syv[fn] = s; t155[fn] = 155.f - s; e128h[fn] = 128.f - 0.5f * s;
    }

    float accS = 0.f;
    #pragma unroll
    for (int fm = 0; fm < 4; fm++) {
        const float4 x4 = *(const float4*)&x2s[wm0 + fm * 16 + q * 4]; // rows q*4..+3
        #pragma unroll
        for (int r = 0; r < 4; r++) {
            const float xvr = (r == 0) ? x4.x : (r == 1) ? x4.y : (r == 2) ? x4.z : x4.w;
            const int ci = wm0 + fm * 16 + q * 4 + r;
            #pragma unroll
            for (int fn = 0; fn < 4; fn++) {
                // d2 = xv + sy - 2*dot ; lhs = xv - 2*dot vs threshold 155 - sy
                float lhs = fmaf(-2.f, acc[fm][fn][r], xvr);
                if (lhs < t155[fn]) {
                    const int cj = wn0 + fn * 16 + lr;
                    if (isDiag && ci == cj) continue;    // diagonal excluded (trace)
                    float term;
                    if (lhs + syv[fn] < 140.f) {
                        // exact fp32 re-dot (rare)
                        const int gi = br * 128 + ci, gj = bc * 128 + cj;
                        const float4* xr = (const float4*)(Xf + (size_t)gi * DDIM);
                        const float4* yr = (const float4*)(Yf + (size_t)gj * DDIM);
                        float dot = 0.f;
                        #pragma unroll 4
                        for (int k = 0; k < 32; k++) {
                            float4 xa = xr[k], yb = yr[k];
                            dot += xa.x * yb.x + xa.y * yb.y + xa.z * yb.z + xa.w * yb.w;
                        }
                        float d2e = fmaxf(xvr + syv[fn] - 2.f * dot, 0.f);
                        term = __expf(fminf(128.f - 0.5f * d2e, 85.f)); // clamp: no inf
                    } else {
                        term = __expf(fmaf(-0.5f, lhs, e128h[fn]));
                    }
                    accS += term;
                }
            }
        }
    }

    // ---- reduce: wave shfl -> LDS -> one plain store per block (no hot atomics)
    #pragma unroll
    for (int off = 32; off; off >>= 1) accS += __shfl_down(accS, off);
    if (lane == 0) red[w] = accS;
    __syncthreads();
    if (tid == 0) {
        double tot = (double)red[0] + (double)red[1] + (double)red[2] + (double)red[3];
        double wgt = (mat < 2 && br != bc) ? 2.0 : 1.0;  // mirror off-diag blocks
        part[bid] = tot * wgt;
        __threadfence();                                  // release part[bid]
        unsigned old = atomicAdd(done, 1u);               // device-scope
        lastFlag = (old == NBLK - 1) ? 1 : 0;
    }
    __syncthreads();

    // ---- last-arriving block reduces all partials and writes the scalar
    if (lastFlag) {
        volatile const double* vp = part;                 // acquire side re-read
        double sxx = 0.0, syy = 0.0, sxy = 0.0;
        for (int i = tid; i < 2080; i += 256)        sxx += vp[i];
        for (int i = 2080 + tid; i < 4160; i += 256) syy += vp[i];
        for (int i = 4160 + tid; i < NBLK; i += 256) sxy += vp[i];
        #pragma unroll
        for (int off = 32; off; off >>= 1) {
            sxx += __shfl_down(sxx, off);
            syy += __shfl_down(syy, off);
            sxy += __shfl_down(sxy, off);
        }
        if (lane == 0) { redd[0][w] = sxx; redd[1][w] = syy; redd[2][w] = sxy; }
        __syncthreads();
        if (tid == 0) {
            const double EM = exp(-128.0);
            double Sxx = (redd[0][0] + redd[0][1] + redd[0][2] + redd[0][3]) * EM;
            double Syy = (redd[1][0] + redd[1][1] + redd[1][2] + redd[1][3]) * EM;
            double Sxy = (redd[2][0] + redd[2][1] + redd[2][2] + redd[2][3]) * EM;
            // Emulate reference fp32 absorption: fl32(N + S_off) - N
            float sumxx = (float)(8192.0 + Sxx);
            float sumyy = (float)(8192.0 + Syy);
            const float scale = 8191.0f / 8192.0f;
            float kxx = (sumxx - 8192.0f) * scale;
            float kyy = (sumyy - 8192.0f) * scale;
            float kxy = (float)(Sxy / (8192.0 * 8192.0));
            out[0] = kxx + kyy - 2.0f * kxy;
        }
    }
}

extern "C" void kernel_launch(void* const* d_in, const int* in_sizes, int n_in,
                              void* d_out, int out_size, void* d_ws, size_t ws_size,
                              hipStream_t stream) {
    const float* z  = (const float*)d_in[0];
    const float* zp = (const float*)d_in[1];
    double* part = (double*)d_ws;                         // 8256 doubles
    unsigned* done = (unsigned*)((char*)d_ws + 66304);
    float* x2 = (float*)((char*)d_ws + 66560);
    float* y2 = (float*)((char*)d_ws + 99328);
    __bf16* Zb  = (__bf16*)((char*)d_ws + 132096);
    __bf16* Zpb = (__bf16*)((char*)d_ws + 2229248);

    prep_kernel<<<1024, 256, 0, stream>>>(z, zp, x2, y2, Zb, Zpb, done);
    mmd_gemm<<<NBLK, 256, 0, stream>>>(z, zp, Zb, Zpb, x2, y2, part, done, (float*)d_out);
}

// Round 9
// 262.189 us; speedup vs baseline: 1.0277x; 1.0277x over previous
//
#include <hip/hip_runtime.h>
#include <hip/hip_bf16.h>
#include <math.h>

// MMD loss, N=8192 D=128 fp32 in, scalar fp32 out.
// Numerics (validated R1-R8, absmax 0): reference's (sum(Kxx)-trace) cancels to
// exactly 0 in fp32; answer = -2*S_xy/N^2 via emulated fp32 absorption. bf16
// MFMA approximates d2; d2<140 -> exact fp32 re-dot (rare); 140..155 -> approx
// exp (truncation past 155 ~1e-3 relative, budget 2%; R8 absmax=0 at 155);
// else skip. Terms scaled e^{+128} -> fp32 accumulators.
//
// R9: R3's skeleton exactly (82.6us gemm: 8256 blk x 512 thr, 2 blk/CU,
// 16 waves/CU -- empirically the occupancy optimum; R5/R7/R8 all regressed
// with fewer resident waves). Epilogue rewritten with explicit __ballot guard:
// theory is R3's 37us VALU was if-converted (predicated) exp on all 32
// elems/thread; ballot forces a wave-uniform branch (hit rate ~6%/iter), so
// fast path = fma + cmp + s_cbranch. Finalize fused via done-counter
// (R5/R8-validated). NO intra-block pipelining (barrier drains vmcnt, R7).

#define NPTS 8192
#define DDIM 128
#define NBLK 8256   // 2080 xx + 2080 yy + 4096 xy (128x128 tiles)

typedef __bf16 bf16x8 __attribute__((ext_vector_type(8)));
typedef float f32x4 __attribute__((ext_vector_type(4)));

// async 16B global->LDS (per-lane global addr; LDS dest = uniform base + lane*16)
#define ASYNC_LD16(gp, lp)                                                        \
    __builtin_amdgcn_global_load_lds(                                             \
        (const __attribute__((address_space(1))) unsigned int*)(gp),              \
        (__attribute__((address_space(3))) unsigned int*)(lp), 16, 0, 0)

// ws layout:
//   0       : double part[8256]  (66048 B per-block partials, scaled e^{+128})
//   66304   : uint done          (zeroed by prep each launch)
//   66560   : float x2[8192]
//   99328   : float y2[8192]
//   132096  : __bf16 Zb [8192*128]  (2 MB)
//   2229248 : __bf16 Zpb[8192*128]  (2 MB)
__global__ void prep_kernel(const float* __restrict__ Z, const float* __restrict__ Zp,
                            float* __restrict__ x2, float* __restrict__ y2,
                            __bf16* __restrict__ Zb, __bf16* __restrict__ Zpb,
                            unsigned* __restrict__ done) {
    if (blockIdx.x == 0 && threadIdx.x == 0) *done = 0u;
    const int row = blockIdx.x * 16 + (threadIdx.x >> 4);   // 0..16383
    const int sub = threadIdx.x & 15;
    const float* src; float* nrm; __bf16* dst; int r;
    if (row < NPTS) { src = Z;  nrm = x2; dst = Zb;  r = row; }
    else            { src = Zp; nrm = y2; dst = Zpb; r = row - NPTS; }
    const float4* p = (const float4*)(src + (size_t)r * DDIM) + sub * 2;
    float4 a = p[0], b = p[1];
    float s = a.x*a.x + a.y*a.y + a.z*a.z + a.w*a.w
            + b.x*b.x + b.y*b.y + b.z*b.z + b.w*b.w;
    bf16x8 o = { (__bf16)a.x, (__bf16)a.y, (__bf16)a.z, (__bf16)a.w,
                 (__bf16)b.x, (__bf16)b.y, (__bf16)b.z, (__bf16)b.w };
    *(bf16x8*)(dst + (size_t)r * DDIM + sub * 8) = o;
    #pragma unroll
    for (int off = 8; off; off >>= 1) s += __shfl_down(s, off, 16);
    if (sub == 0) nrm[r] = s;
}

__launch_bounds__(512, 2)
__global__ void mmd_gemm(const float* __restrict__ Z, const float* __restrict__ Zp,
                         const __bf16* __restrict__ Zb, const __bf16* __restrict__ Zpb,
                         const float* __restrict__ x2g, const float* __restrict__ y2g,
                         double* __restrict__ part, unsigned* __restrict__ done,
                         float* __restrict__ out) {
    // ---- decode linear block id -> (mat, br, bc); triangles packed
    const int bid = blockIdx.x;
    int mat, br, bc;
    if (bid < 4160) {
        mat = (bid < 2080) ? 0 : 1;
        int idx = bid - mat * 2080;
        int r = (int)((sqrtf(8.f * (float)idx + 1.f) - 1.f) * 0.5f);
        while ((r + 1) * (r + 2) / 2 <= idx) ++r;
        while (r * (r + 1) / 2 > idx) --r;
        br = idx - r * (r + 1) / 2;   // br <= bc: upper triangle
        bc = r;
    } else {
        mat = 2;
        int idx = bid - 4160;
        br = idx >> 6; bc = idx & 63;
    }
    const float*  Xf = (mat == 1) ? Zp  : Z;
    const float*  Yf = (mat == 0) ? Z   : Zp;
    const __bf16* Xb = (mat == 1) ? Zpb : Zb;
    const __bf16* Yb = (mat == 0) ? Zb  : Zpb;
    const float*  xn = (mat == 1) ? y2g : x2g;
    const float*  yn = (mat == 0) ? x2g : y2g;

    __shared__ __bf16 As[128 * DDIM];   // 32 KB, XOR-swizzled 16B chunks
    __shared__ __bf16 Bs[128 * DDIM];   // 32 KB
    __shared__ float x2s[128], y2s[128];
    __shared__ float red[8];
    __shared__ double redd[3][8];
    __shared__ int lastFlag;

    const int tid = threadIdx.x;
    const int w = tid >> 6, lane = tid & 63;

    // ---- stage bf16 tiles via global_load_lds; LDS[row][s] = G[row][s^(row&15)]
    // waves 0-3 -> A (8 x 1KB insts each), waves 4-7 -> B. R3 geometry exactly
    // (measured 0 bank conflicts).
    {
        const __bf16* src = (w < 4) ? (Xb + (size_t)br * 128 * DDIM)
                                    : (Yb + (size_t)bc * 128 * DDIM);
        char* dstB = (char*)((w < 4) ? As : Bs);
        const int w4 = w & 3;
        #pragma unroll
        for (int t = 0; t < 8; t++) {
            int row = w4 * 32 + t * 4 + (lane >> 4);
            int c = (lane & 15) ^ (row & 15);
            ASYNC_LD16(src + (size_t)row * DDIM + c * 8, dstB + w4 * 8192 + t * 1024);
        }
    }
    if (tid < 128)      x2s[tid]       = xn[br * 128 + tid];
    else if (tid < 256) y2s[tid - 128] = yn[bc * 128 + (tid - 128)];
    __syncthreads();

    // ---- MFMA: 8 waves in 4x2, each 32x64 (2x4 frags of 16x16x32) -- R3 exact
    const int lr = lane & 15;
    const int q  = lane >> 4;           // 0..3
    const int wm0 = (w >> 1) * 32;
    const int wn0 = (w & 1) * 64;

    f32x4 acc[2][4] = {};
    #pragma unroll
    for (int ks = 0; ks < 4; ks++) {
        const int chunk = ks * 4 + q;
        bf16x8 a[2], b[4];
        #pragma unroll
        for (int f = 0; f < 2; f++) {
            int row = wm0 + f * 16 + lr;              // row&15 == lr
            a[f] = *(const bf16x8*)((const char*)As + row * 256 + ((chunk ^ lr) * 16));
        }
        #pragma unroll
        for (int f = 0; f < 4; f++) {
            int row = wn0 + f * 16 + lr;
            b[f] = *(const bf16x8*)((const char*)Bs + row * 256 + ((chunk ^ lr) * 16));
        }
        #pragma unroll
        for (int fm = 0; fm < 2; fm++)
            #pragma unroll
            for (int fn = 0; fn < 4; fn++)
                acc[fm][fn] = __builtin_amdgcn_mfma_f32_16x16x32_bf16(
                    a[fm], b[fn], acc[fm][fn], 0, 0, 0);
    }

    // ---- epilogue: ballot-guarded tiers. Fast path = fma + cmp + s_cbranch.
    // C/D layout: col=lane&15, row=q*4+reg [m89/m91]
    const int row0 = q * 4;
    const bool isDiag = (mat < 2) && (br == bc);
    float t155[4], syv[4], e128h[4];
    #pragma unroll
    for (int fn = 0; fn < 4; fn++) {
        float s = y2s[wn0 + fn * 16 + lr];
        syv[fn] = s; t155[fn] = 155.f - s; e128h[fn] = 128.f - 0.5f * s;
    }

    float accS = 0.f;
    #pragma unroll
    for (int fm = 0; fm < 2; fm++) {
        #pragma unroll
        for (int r = 0; r < 4; r++) {
            const int ci = wm0 + fm * 16 + row0 + r;
            const float xvr = x2s[ci];
            #pragma unroll
            for (int fn = 0; fn < 4; fn++) {
                float lhs = fmaf(-2.f, acc[fm][fn][r], xvr);   // d2 - sy
                bool hit = lhs < t155[fn];
                if (__ballot(hit)) {              // wave-uniform skip of rare body
                    if (hit) {
                        const int cj = wn0 + fn * 16 + lr;
                        if (!(isDiag && ci == cj)) {           // diagonal excluded
                            float term;
                            if (lhs + syv[fn] < 140.f) {
                                // exact fp32 re-dot (rare)
                                const int gi = br * 128 + ci, gj = bc * 128 + cj;
                                const float4* xr = (const float4*)(Xf + (size_t)gi * DDIM);
                                const float4* yr = (const float4*)(Yf + (size_t)gj * DDIM);
                                float dot = 0.f;
                                #pragma unroll 4
                                for (int k = 0; k < 32; k++) {
                                    float4 xa = xr[k], yb = yr[k];
                                    dot += xa.x * yb.x + xa.y * yb.y + xa.z * yb.z + xa.w * yb.w;
                                }
                                float d2e = fmaxf(xvr + syv[fn] - 2.f * dot, 0.f);
                                term = __expf(fminf(128.f - 0.5f * d2e, 85.f));
                            } else {
                                term = __expf(fmaf(-0.5f, lhs, e128h[fn]));
                            }
                            accS += term;
                        }
                    }
                }
            }
        }
    }

    // ---- reduce: fp32 wave shfl -> LDS -> one plain store per block
    #pragma unroll
    for (int off = 32; off; off >>= 1) accS += __shfl_down(accS, off);
    if (lane == 0) red[w] = accS;
    __syncthreads();
    if (tid == 0) {
        double tot = 0.0;
        #pragma unroll
        for (int i = 0; i < 8; i++) tot += (double)red[i];
        double wgt = (mat < 2 && br != bc) ? 2.0 : 1.0;  // mirror off-diag blocks
        part[bid] = tot * wgt;
        __threadfence();                                  // release part[bid]
        unsigned old = atomicAdd(done, 1u);               // device-scope
        lastFlag = (old == NBLK - 1) ? 1 : 0;
    }
    __syncthreads();

    // ---- last-arriving block reduces all partials and writes the scalar
    if (lastFlag) {
        volatile const double* vp = part;                 // acquire-side re-read
        double sxx = 0.0, syy = 0.0, sxy = 0.0;
        for (int i = tid; i < 2080; i += 512)        sxx += vp[i];
        for (int i = 2080 + tid; i < 4160; i += 512) syy += vp[i];
        for (int i = 4160 + tid; i < NBLK; i += 512) sxy += vp[i];
        #pragma unroll
        for (int off = 32; off; off >>= 1) {
            sxx += __shfl_down(sxx, off);
            syy += __shfl_down(syy, off);
            sxy += __shfl_down(sxy, off);
        }
        if (lane == 0) { redd[0][w] = sxx; redd[1][w] = syy; redd[2][w] = sxy; }
        __syncthreads();
        if (tid == 0) {
            double Sxx = 0.0, Syy = 0.0, Sxy = 0.0;
            #pragma unroll
            for (int i = 0; i < 8; i++) { Sxx += redd[0][i]; Syy += redd[1][i]; Sxy += redd[2][i]; }
            const double EM = exp(-128.0);
            Sxx *= EM; Syy *= EM; Sxy *= EM;
            // Emulate reference fp32 absorption: fl32(N + S_off) - N
            float sumxx = (float)(8192.0 + Sxx);
            float sumyy = (float)(8192.0 + Syy);
            const float scale = 8191.0f / 8192.0f;
            float kxx = (sumxx - 8192.0f) * scale;
            float kyy = (sumyy - 8192.0f) * scale;
            float kxy = (float)(Sxy / (8192.0 * 8192.0));
            out[0] = kxx + kyy - 2.0f * kxy;
        }
    }
}

extern "C" void kernel_launch(void* const* d_in, const int* in_sizes, int n_in,
                              void* d_out, int out_size, void* d_ws, size_t ws_size,
                              hipStream_t stream) {
    const float* z  = (const float*)d_in[0];
    const float* zp = (const float*)d_in[1];
    double* part = (double*)d_ws;                         // 8256 doubles
    unsigned* done = (unsigned*)((char*)d_ws + 66304);
    float* x2 = (float*)((char*)d_ws + 66560);
    float* y2 = (float*)((char*)d_ws + 99328);
    __bf16* Zb  = (__bf16*)((char*)d_ws + 132096);
    __bf16* Zpb = (__bf16*)((char*)d_ws + 2229248);

    prep_kernel<<<1024, 256, 0, stream>>>(z, zp, x2, y2, Zb, Zpb, done);
    mmd_gemm<<<NBLK, 512, 0, stream>>>(z, zp, Zb, Zpb, x2, y2, part, done, (float*)d_out);
}